// Round 7
// baseline (38381.348 us; speedup 1.0000x reference)
//
#include <hip/hip_runtime.h>
#include <math.h>

// Problem constants
#define D_MODEL 1024
#define N_WIN   240
#define TOK     256
#define NH      16
#define DH      64
#define CHUNK   8
#define NCHUNK  30
#define WIN     ((size_t)TOK * D_MODEL)

typedef unsigned short ushort_t;
typedef unsigned long long ull_t;
typedef __attribute__((ext_vector_type(8))) short short8;
typedef __attribute__((ext_vector_type(4))) float floatx4;

__device__ __forceinline__ ushort_t f2bf(float f) {   // RNE
    unsigned u = __float_as_uint(f);
    unsigned lsb = (u >> 16) & 1u;
    u += 0x7fffu + lsb;
    return (ushort_t)(u >> 16);
}

// ---------------------------------------------------------------------------
// L3-coherent access primitives: relaxed system-scope atomics compile to
// global_load/store ... sc0 sc1 (bypass L1/L2, served at the coherence
// point). Used for ALL cross-WG data inside the coop kernel -> no
// __threadfence (L2 writeback/invalidate) ever needed.
// ---------------------------------------------------------------------------
__device__ __forceinline__ void st2_sys(ushort_t* p, ushort_t v) {
    __hip_atomic_store(p, v, __ATOMIC_RELAXED, __HIP_MEMORY_SCOPE_SYSTEM);
}
__device__ __forceinline__ ull_t ld8_sys(const ushort_t* p) {
    return __hip_atomic_load((const ull_t*)p, __ATOMIC_RELAXED,
                             __HIP_MEMORY_SCOPE_SYSTEM);
}
__device__ __forceinline__ short8 ld16_sys(const ushort_t* p) {
    union { ull_t u[2]; short8 s; } c;
    c.u[0] = ld8_sys(p); c.u[1] = ld8_sys(p + 4);
    return c.s;
}
__device__ __forceinline__ uint4 ld16_sys_u4(const ushort_t* p) {
    union { ull_t u[2]; uint4 v; } c;
    c.u[0] = ld8_sys(p); c.u[1] = ld8_sys(p + 4);
    return c.v;
}

// async global->LDS, 16B per lane (phase-1 GEMM staging)
#define GLDS(g, l) __builtin_amdgcn_global_load_lds( \
    (const __attribute__((address_space(1))) unsigned int*)(g), \
    (__attribute__((address_space(3))) unsigned int*)(l), 16, 0, 0)

// ---------------------------------------------------------------------------
// Tree barrier, fence-free. Caller must __syncthreads() before bar_signal
// (pre-barrier vmcnt(0) drains this WG's write-through stores to L3).
// ---------------------------------------------------------------------------
__device__ __forceinline__ void bar_signal(unsigned* base, int g,
                                           unsigned subT, unsigned rootT,
                                           unsigned s)
{
    __asm__ __volatile__("" ::: "memory");
    __builtin_amdgcn_s_waitcnt(0);   // belt-and-suspenders store drain
    unsigned old = __hip_atomic_fetch_add(base + g * 32, 1u, __ATOMIC_RELAXED,
                                          __HIP_MEMORY_SCOPE_SYSTEM);
    if (old == subT - 1u) {
        unsigned r = __hip_atomic_fetch_add(base + 256, 1u, __ATOMIC_RELAXED,
                                            __HIP_MEMORY_SCOPE_SYSTEM);
        if (r == rootT - 1u)
            __hip_atomic_store(base + 288, s, __ATOMIC_RELAXED,
                               __HIP_MEMORY_SCOPE_SYSTEM);
    }
}
__device__ __forceinline__ void bar_wait(unsigned* base, unsigned s)
{
    while (__hip_atomic_load(base + 288, __ATOMIC_RELAXED,
                             __HIP_MEMORY_SCOPE_SYSTEM) < s)
        __builtin_amdgcn_s_sleep(1);
    __asm__ __volatile__("" ::: "memory");
}

// ---------------------------------------------------------------------------
// fp32 -> bf16 cast
// ---------------------------------------------------------------------------
__global__ __launch_bounds__(256) void cast_bf_k(
    const float* __restrict__ s, ushort_t* __restrict__ d, int n)
{
    int i = (blockIdx.x * 256 + threadIdx.x) * 4;
    if (i >= n) return;
    float4 v = *(const float4*)(s + i);
    ushort4 o;
    o.x = f2bf(v.x); o.y = f2bf(v.y); o.z = f2bf(v.z); o.w = f2bf(v.w);
    *(ushort4*)(d + i) = o;
}

// ---------------------------------------------------------------------------
// Phase-1 bf16 MFMA GEMM core (m97 structure), 128x128 tile, BK=32.
// ---------------------------------------------------------------------------
template<bool GATHER>
__device__ __forceinline__ void gemm_core(
    const ushort_t* __restrict__ A, int lda, int w0,
    const ushort_t* __restrict__ W, const float* __restrict__ bias,
    ushort_t* __restrict__ Cb, float* __restrict__ Cf, int ldc,
    int K, int m0, int n0, int co, int relu)
{
    __shared__ ushort_t As[128 * 32];
    __shared__ ushort_t Bs[128 * 32];
    const int tid = threadIdx.x;
    const int wave = tid >> 6, lane = tid & 63;
    const int wm = wave & 1, wn = wave >> 1;

    int r0 = m0 + (tid >> 2), r1 = r0 + 64;
    if (GATHER) {
        r0 = (w0 + (r0 >> 8)) * 16 + (r0 & 255);
        r1 = (w0 + (r1 >> 8)) * 16 + (r1 & 255);
    }
    const int kcol = (tid & 3) * 8;
    const ushort_t* gA0 = A + (size_t)r0 * lda + kcol;
    const ushort_t* gA1 = A + (size_t)r1 * lda + kcol;
    const ushort_t* pW  = W + (size_t)n0 * K;
    const ushort_t* gB0 = pW + (size_t)(tid >> 2) * K + kcol;
    const ushort_t* gB1 = gB0 + (size_t)64 * K;
    ushort_t* lA = As + wave * 512;
    ushort_t* lB = Bs + wave * 512;

    floatx4 acc[4][4];
#pragma unroll
    for (int i = 0; i < 4; ++i)
#pragma unroll
        for (int j = 0; j < 4; ++j) acc[i][j] = (floatx4){0.f, 0.f, 0.f, 0.f};

    const int fr = lane & 15, fk = (lane >> 4) * 8;
    const int arow = (wm * 64 + fr) * 32 + fk;
    const int brow = (wn * 64 + fr) * 32 + fk;

    for (int k0 = 0; k0 < K; k0 += 32) {
        GLDS(gA0 + k0, lA);
        GLDS(gA1 + k0, lA + 2048);
        GLDS(gB0 + k0, lB);
        GLDS(gB1 + k0, lB + 2048);
        __syncthreads();
        short8 a[4], b[4];
#pragma unroll
        for (int mi = 0; mi < 4; ++mi) a[mi] = *(const short8*)&As[arow + mi * 512];
#pragma unroll
        for (int ni = 0; ni < 4; ++ni) b[ni] = *(const short8*)&Bs[brow + ni * 512];
#pragma unroll
        for (int mi = 0; mi < 4; ++mi)
#pragma unroll
            for (int ni = 0; ni < 4; ++ni)
                acc[mi][ni] = __builtin_amdgcn_mfma_f32_16x16x32_bf16(
                    a[mi], b[ni], acc[mi][ni], 0, 0, 0);
        __syncthreads();
    }

    const int crq = (lane >> 4) * 4;
    const int ccol = lane & 15;
#pragma unroll
    for (int mi = 0; mi < 4; ++mi) {
#pragma unroll
        for (int ni = 0; ni < 4; ++ni) {
            int lc = wn * 64 + ni * 16 + ccol;
            float bz = bias[n0 + lc];
#pragma unroll
            for (int rg = 0; rg < 4; ++rg) {
                int row = m0 + wm * 64 + mi * 16 + crq + rg;
                float v = acc[mi][ni][rg] + bz;
                if (relu) v = fmaxf(v, 0.f);
                size_t off = (size_t)row * ldc + co + lc;
                if (Cb) Cb[off] = f2bf(v);
                if (Cf) Cf[off] = v;
            }
        }
    }
}

__global__ __launch_bounds__(256) void gemm_bf_k(
    const ushort_t* __restrict__ A, int lda,
    const ushort_t* __restrict__ W, const float* __restrict__ bias,
    ushort_t* __restrict__ Cb, float* __restrict__ Cf, int ldc,
    int K, int relu)
{
    gemm_core<false>(A, lda, 0, W, bias, Cb, Cf, ldc, K,
                     blockIdx.y * 128, blockIdx.x * 128, blockIdx.x * 128, relu);
}

__global__ __launch_bounds__(256) void gemm_qkv_k(
    const ushort_t* __restrict__ path_bf, const ushort_t* __restrict__ W,
    const float* __restrict__ bias, ushort_t* __restrict__ Cb, int w0)
{
    gemm_core<true>(path_bf, 1024, w0, W, bias, Cb, nullptr, 3072, 1024,
                    blockIdx.y * 128, blockIdx.x * 128, blockIdx.x * 128, 0);
}

// ---------------------------------------------------------------------------
// Shared MFMA attention core. SYS: K/V loads + O stores go through L3
// (system-scope relaxed atomics); Q always normal cached loads.
// ---------------------------------------------------------------------------
#define PLD 260
#define VLD 132

struct ScanShared {
    ushort_t P[64 * PLD];
    ushort_t VT[64 * VLD];
    float    l[64];
};

template<bool SYS>
__device__ __forceinline__ void attn_core(
    int h, int rs, int tid,
    const ushort_t* __restrict__ Q, int ldq,
    const ushort_t* __restrict__ K, const ushort_t* __restrict__ V, int ldkv,
    ushort_t* __restrict__ O, int ldo, ScanShared& sh)
{
    const int wave = tid >> 6, lane = tid & 63;
    const int fr = lane & 15, q = lane >> 4, fk = q * 8;
    const ushort_t* Qh = Q + (size_t)(rs * 64) * ldq + h * 64;
    const ushort_t* Kh = K + h * 64;
    const ushort_t* Vh = V + h * 64;
    const int m0 = wave * 16;

    floatx4 s[16];
#pragma unroll
    for (int nt = 0; nt < 16; ++nt) s[nt] = (floatx4){0.f, 0.f, 0.f, 0.f};
#pragma unroll
    for (int kc = 0; kc < 64; kc += 32) {
        short8 a = *(const short8*)(Qh + (size_t)(m0 + fr) * ldq + kc + fk);
#pragma unroll
        for (int nt = 0; nt < 16; ++nt) {
            const ushort_t* kp = Kh + (size_t)(nt * 16 + fr) * ldkv + kc + fk;
            short8 b = SYS ? ld16_sys(kp) : *(const short8*)kp;
            s[nt] = __builtin_amdgcn_mfma_f32_16x16x32_bf16(a, b, s[nt], 0, 0, 0);
        }
    }

    float rmax[4] = {-INFINITY, -INFINITY, -INFINITY, -INFINITY};
#pragma unroll
    for (int nt = 0; nt < 16; ++nt)
#pragma unroll
        for (int rg = 0; rg < 4; ++rg) rmax[rg] = fmaxf(rmax[rg], s[nt][rg]);
#pragma unroll
    for (int d = 1; d < 16; d <<= 1)
#pragma unroll
        for (int rg = 0; rg < 4; ++rg)
            rmax[rg] = fmaxf(rmax[rg], __shfl_xor(rmax[rg], d));

    float rsum[4] = {0.f, 0.f, 0.f, 0.f};
#pragma unroll
    for (int nt = 0; nt < 16; ++nt) {
#pragma unroll
        for (int rg = 0; rg < 4; ++rg) {
            float p = __expf((s[nt][rg] - rmax[rg]) * 0.125f);
            rsum[rg] += p;
            sh.P[(m0 + q * 4 + rg) * PLD + nt * 16 + fr] = f2bf(p);
        }
    }
#pragma unroll
    for (int d = 1; d < 16; d <<= 1)
#pragma unroll
        for (int rg = 0; rg < 4; ++rg) rsum[rg] += __shfl_xor(rsum[rg], d);
    if (fr == 0) {
#pragma unroll
        for (int rg = 0; rg < 4; ++rg) sh.l[m0 + q * 4 + rg] = rsum[rg];
    }
    __syncthreads();

    floatx4 o[4];
#pragma unroll
    for (int i = 0; i < 4; ++i) o[i] = (floatx4){0.f, 0.f, 0.f, 0.f};

#pragma unroll
    for (int half = 0; half < 2; ++half) {
        {
            int r = tid & 127, cp = tid >> 7;
            const ushort_t* vrow = Vh + (size_t)(half * 128 + r) * ldkv + cp * 32;
#pragma unroll
            for (int c = 0; c < 4; ++c) {
                uint4 pk = SYS ? ld16_sys_u4(vrow + c * 8)
                               : *(const uint4*)(vrow + c * 8);
                int d0 = cp * 32 + c * 8;
                sh.VT[(d0 + 0) * VLD + r] = (ushort_t)(pk.x & 0xffff);
                sh.VT[(d0 + 1) * VLD + r] = (ushort_t)(pk.x >> 16);
                sh.VT[(d0 + 2) * VLD + r] = (ushort_t)(pk.y & 0xffff);
                sh.VT[(d0 + 3) * VLD + r] = (ushort_t)(pk.y >> 16);
                sh.VT[(d0 + 4) * VLD + r] = (ushort_t)(pk.z & 0xffff);
                sh.VT[(d0 + 5) * VLD + r] = (ushort_t)(pk.z >> 16);
                sh.VT[(d0 + 6) * VLD + r] = (ushort_t)(pk.w & 0xffff);
                sh.VT[(d0 + 7) * VLD + r] = (ushort_t)(pk.w >> 16);
            }
        }
        __syncthreads();
#pragma unroll
        for (int ks = 0; ks < 4; ++ks) {
            short8 a = *(const short8*)&sh.P[(m0 + fr) * PLD + half * 128 + ks * 32 + fk];
#pragma unroll
            for (int nt2 = 0; nt2 < 4; ++nt2) {
                short8 b = *(const short8*)&sh.VT[(nt2 * 16 + fr) * VLD + ks * 32 + fk];
                o[nt2] = __builtin_amdgcn_mfma_f32_16x16x32_bf16(a, b, o[nt2], 0, 0, 0);
            }
        }
        __syncthreads();
    }

    float linv[4];
#pragma unroll
    for (int rg = 0; rg < 4; ++rg) linv[rg] = 1.f / sh.l[m0 + q * 4 + rg];
#pragma unroll
    for (int nt2 = 0; nt2 < 4; ++nt2)
#pragma unroll
        for (int rg = 0; rg < 4; ++rg) {
            int row = rs * 64 + m0 + q * 4 + rg;
            ushort_t* op = O + (size_t)row * ldo + h * 64 + nt2 * 16 + fr;
            ushort_t v = f2bf(o[nt2][rg] * linv[rg]);
            if (SYS) st2_sys(op, v); else *op = v;
        }
}

// Phase-1 standalone MFMA attention: grid (4 row-slices, NH, batch)
__global__ __launch_bounds__(256) void attn_mfma_k(
    const ushort_t* __restrict__ qkv, ushort_t* __restrict__ ao)
{
    __shared__ ScanShared sh;
    const int rs = blockIdx.x, h = blockIdx.y, b = blockIdx.z;
    const ushort_t* base = qkv + (size_t)b * TOK * 3072;
    attn_core<false>(h, rs, threadIdx.x, base, 3072, base + 1024, base + 2048,
                     3072, ao + (size_t)b * TOK * 1024, 1024, sh);
}

// ---------------------------------------------------------------------------
// Register-weight tall-skinny GEMM (sys data path):
// C[256 x 16] = A[256 x 1024] @ Wreg^T + bz.  A via L3 loads, C via L3 stores.
// ---------------------------------------------------------------------------
__device__ __forceinline__ void ts_gemm_reg(
    const ushort_t* __restrict__ A, const short8* wreg, float bz,
    ushort_t* __restrict__ Cb, float* __restrict__ Cf, int ldc, int cc,
    int wave, int lane)
{
    const int fr = lane & 15, fk = (lane >> 4) * 8, q = lane >> 4;
    const int m0v = wave * 64;
    floatx4 acc[4];
#pragma unroll
    for (int i = 0; i < 4; ++i) acc[i] = (floatx4){0.f, 0.f, 0.f, 0.f};
    const ushort_t* aptr = A + (size_t)(m0v + fr) * 1024 + fk;
#pragma unroll
    for (int k = 0; k < 32; ++k) {
#pragma unroll
        for (int mi = 0; mi < 4; ++mi) {
            short8 a = ld16_sys(aptr + (size_t)(mi * 16) * 1024 + k * 32);
            acc[mi] = __builtin_amdgcn_mfma_f32_16x16x32_bf16(a, wreg[k], acc[mi], 0, 0, 0);
        }
    }
#pragma unroll
    for (int mi = 0; mi < 4; ++mi) {
#pragma unroll
        for (int rg = 0; rg < 4; ++rg) {
            int row = m0v + mi * 16 + q * 4 + rg;
            float v = acc[mi][rg] + bz;
            size_t off = (size_t)row * ldc + cc + fr;
            st2_sys(Cb + off, f2bf(v));
            if (Cf) Cf[off] = v;
        }
    }
}

// ===========================================================================
// Cooperative phase-2 kernel. Grid 192 WGs x 256 thr (1 block/CU).
//  Role A (WGs 64..191): KV projection, weights in 128 VGPRs.
//  Role B+C (WGs 0..63): MFMA attention + out projection.
// All cross-WG data (cum, KVb, AO2) via system-scope (L3) atomics;
// barriers fence-free.
// ===========================================================================
__global__ __launch_bounds__(256, 1) void scan_coop_k(
    const ushort_t* __restrict__ Qchunk, int i0, int w0, int nsteps,
    ushort_t* __restrict__ cum, ushort_t* __restrict__ KVb,
    ushort_t* __restrict__ AO2,
    const ushort_t* __restrict__ w_in2, const float* __restrict__ b_in2,
    const ushort_t* __restrict__ w_out2, const float* __restrict__ b_out2,
    float* __restrict__ outp, unsigned* __restrict__ bar, unsigned s0)
{
    __shared__ ScanShared sh;
    const int wg = blockIdx.x, tid = threadIdx.x;
    const int wave = tid >> 6, lane = tid & 63;
    const int fr = lane & 15, fk = (lane >> 4) * 8;
    unsigned* barA = bar;
    unsigned* barB = bar + 320;
    unsigned* barC = bar + 640;

    if (wg >= 64) {
        // ---------------- role A: KV = cum @ wkv^T ----------------
        const int n0 = (wg - 64) * 16;
        const int g = (wg - 64) & 7;
        short8 wreg[32];
        const ushort_t* Wn = w_in2 + (size_t)(1024 + n0 + fr) * 1024 + fk;
#pragma unroll
        for (int k = 0; k < 32; ++k) wreg[k] = *(const short8*)(Wn + k * 32);
        const float bz = b_in2[1024 + n0 + fr];

        unsigned s = s0;
        for (int t = 0; t < nsteps; ++t, ++s) {
            ts_gemm_reg(cum, wreg, bz, KVb, nullptr, 2048, n0, wave, lane);
            __syncthreads();
            if (tid == 0) {
                bar_signal(barA, g, 16u * s, 8u * s, s);   // publish KVb
                bar_wait(barC, s);                         // wait for cum_t
            }
            __syncthreads();
        }
    } else {
        // ---------------- role B+C ----------------
        const int h = wg >> 2, rs = wg & 3;     // stage B assignment
        const int n0 = wg * 16;                 // stage C columns
        const int g = wg & 3;
        short8 wreg[32];
        const ushort_t* Wn = w_out2 + (size_t)(n0 + fr) * 1024 + fk;
#pragma unroll
        for (int k = 0; k < 32; ++k) wreg[k] = *(const short8*)(Wn + k * 32);
        const float bz = b_out2[n0 + fr];

        unsigned s = s0;
        for (int t = 0; t < nsteps; ++t, ++s) {
            const int i = i0 + t;
            if (tid == 0) bar_wait(barA, s);    // KVb ready
            __syncthreads();
            attn_core<true>(h, rs, tid, Qchunk + (size_t)(i - w0) * WIN, 1024,
                            KVb, KVb + 1024, 2048, AO2, 1024, sh);
            __syncthreads();
            if (tid == 0) {
                bar_signal(barB, g, 16u * s, 4u * s, s);   // AO2 published
                bar_wait(barB, s);
            }
            __syncthreads();
            float* Cf = (i == N_WIN - 1) ? outp : nullptr;
            ts_gemm_reg(AO2, wreg, bz, cum, Cf, 1024, n0, wave, lane);
            __syncthreads();
            if (tid == 0) bar_signal(barC, g, 16u * s, 4u * s, s);  // cum ready
            __syncthreads();
        }
    }
}

// ---------------------------------------------------------------------------
extern "C" void kernel_launch(void* const* d_in, const int* in_sizes, int n_in,
                              void* d_out, int out_size, void* d_ws, size_t ws_size,
                              hipStream_t stream)
{
    const float* path   = (const float*)d_in[0];
    const float* w_in1  = (const float*)d_in[1];
    const float* b_in1  = (const float*)d_in[2];
    const float* w_out1 = (const float*)d_in[3];
    const float* b_out1 = (const float*)d_in[4];
    const float* w_lin  = (const float*)d_in[5];
    const float* b_lin  = (const float*)d_in[6];
    const float* w_in2  = (const float*)d_in[7];
    const float* b_in2  = (const float*)d_in[8];
    const float* w_out2 = (const float*)d_in[9];
    const float* b_out2 = (const float*)d_in[10];
    float* out = (float*)d_out;

    // workspace: barriers (8 KB) then bf16 buffers (~55 MB)
    unsigned* bar = (unsigned*)d_ws;
    ushort_t* ws = (ushort_t*)d_ws + 4096;
    ushort_t* path_bf  = ws;                              // 4096*1024
    ushort_t* w_in1_bf = path_bf  + (size_t)4096 * 1024;  // 3072*1024
    ushort_t* w_out1_bf= w_in1_bf + (size_t)3072 * 1024;
    ushort_t* w_lin_bf = w_out1_bf+ (size_t)1024 * 1024;
    ushort_t* w_in2_bf = w_lin_bf + (size_t)1024 * 1024;  // 3072*1024
    ushort_t* w_out2_bf= w_in2_bf + (size_t)3072 * 1024;
    ushort_t* qkv_bf   = w_out2_bf+ (size_t)1024 * 1024;  // 2048*3072
    ushort_t* ybuf_bf  = qkv_bf;                          // alias (qkv dead)
    ushort_t* ao_bf    = qkv_bf   + (size_t)2048 * 3072;  // 2048*1024
    ushort_t* Xchunk   = ao_bf    + (size_t)2048 * 1024;  // 2048*1024
    ushort_t* Qchunk   = Xchunk   + (size_t)2048 * 1024;  // 2048*1024
    ushort_t* KVb      = Qchunk   + (size_t)2048 * 1024;  // 256*2048
    ushort_t* AO2      = KVb + 2 * WIN;                   // 256*1024
    ushort_t* cum      = AO2 + WIN;                       // 256*1024

    hipMemsetAsync(bar, 0, 8192, stream);

    cast_bf_k<<<4096, 256, 0, stream>>>(path,  path_bf,  4096 * 1024);
    cast_bf_k<<<3072, 256, 0, stream>>>(w_in1, w_in1_bf, 3072 * 1024);
    cast_bf_k<<<1024, 256, 0, stream>>>(w_out1, w_out1_bf, 1024 * 1024);
    cast_bf_k<<<1024, 256, 0, stream>>>(w_lin, w_lin_bf, 1024 * 1024);
    cast_bf_k<<<3072, 256, 0, stream>>>(w_in2, w_in2_bf, 3072 * 1024);
    cast_bf_k<<<1024, 256, 0, stream>>>(w_out2, w_out2_bf, 1024 * 1024);

    unsigned sbase = 1;
    for (int c = 0; c < NCHUNK; ++c) {
        int w0 = c * CHUNK;
        // ---- Phase 1 for windows [w0, w0+CHUNK) ----
        gemm_qkv_k<<<dim3(24, 16), 256, 0, stream>>>(
            path_bf, w_in1_bf, b_in1, qkv_bf, w0);
        attn_mfma_k<<<dim3(4, NH, CHUNK), 256, 0, stream>>>(qkv_bf, ao_bf);
        gemm_bf_k<<<dim3(8, 16), 256, 0, stream>>>(
            ao_bf, 1024, w_out1_bf, b_out1, ybuf_bf, nullptr, 1024, 1024, 0);
        gemm_bf_k<<<dim3(8, 16), 256, 0, stream>>>(
            ybuf_bf, 1024, w_lin_bf, b_lin, Xchunk, nullptr, 1024, 1024, 1);
        // Q for the whole chunk (rows 0..1023 of w_in2 are wq)
        gemm_bf_k<<<dim3(8, 16), 256, 0, stream>>>(
            Xchunk, 1024, w_in2_bf, b_in2, Qchunk, nullptr, 1024, 1024, 0);

        // ---- Phase 2: one cooperative launch per chunk ----
        if (c == 0) {
            hipMemcpyAsync(cum, Xchunk, WIN * sizeof(ushort_t),
                           hipMemcpyDeviceToDevice, stream);
        }
        int i0 = (c == 0) ? 1 : w0;
        int nsteps = (c == 0) ? CHUNK - 1 : CHUNK;
        const ushort_t* QchunkP = Qchunk;
        ushort_t *cumP = cum, *KVbP = KVb, *AO2P = AO2;
        const ushort_t *win2P = w_in2_bf, *wout2P = w_out2_bf;
        const float *bin2P = b_in2, *bout2P = b_out2;
        float* outP = out;
        unsigned* barP = bar;
        unsigned sb = sbase;
        void* args[] = {&QchunkP, &i0, &w0, &nsteps, &cumP, &KVbP, &AO2P,
                        &win2P, &bin2P, &wout2P, &bout2P, &outP, &barP, &sb};
        hipLaunchCooperativeKernel((void*)scan_coop_k, dim3(192), dim3(256),
                                   args, 0, stream);
        sbase += (unsigned)nsteps;
    }
}

// Round 8
// 23440.221 us; speedup vs baseline: 1.6374x; 1.6374x over previous
//
#include <hip/hip_runtime.h>
#include <math.h>

// Problem constants
#define D_MODEL 1024
#define N_WIN   240
#define TOK     256
#define NH      16
#define DH      64
#define CHUNK   8
#define NCHUNK  30
#define WIN     ((size_t)TOK * D_MODEL)

typedef unsigned short ushort_t;
typedef __attribute__((ext_vector_type(8))) short short8;
typedef __attribute__((ext_vector_type(4))) float floatx4;

__device__ __forceinline__ ushort_t f2bf(float f) {   // RNE
    unsigned u = __float_as_uint(f);
    unsigned lsb = (u >> 16) & 1u;
    u += 0x7fffu + lsb;
    return (ushort_t)(u >> 16);
}

// ---------------------------------------------------------------------------
// Write-through 2B store (lands at the coherence point; makes release fences
// need only vmcnt(0), no L2 writeback). Loads stay NORMAL cached loads.
// ---------------------------------------------------------------------------
__device__ __forceinline__ void st2_wt(ushort_t* p, ushort_t v) {
    unsigned vv = v;
    asm volatile("global_store_short %0, %1, off sc1"
                 :: "v"(p), "v"(vv) : "memory");
}
__device__ __forceinline__ void rel_drain() {
    asm volatile("s_waitcnt vmcnt(0)" ::: "memory");
}
__device__ __forceinline__ void acq_inv() {
    asm volatile("buffer_inv sc1" ::: "memory");   // cheap acquire: tag inv
}

// async global->LDS, 16B per lane (phase-1 GEMM staging)
#define GLDS(g, l) __builtin_amdgcn_global_load_lds( \
    (const __attribute__((address_space(1))) unsigned int*)(g), \
    (__attribute__((address_space(3))) unsigned int*)(l), 16, 0, 0)

// ---------------------------------------------------------------------------
// Tree barrier: agent-scope atomics (round-6-proven), cheap fences.
// Caller must __syncthreads() before bar_signal.
// ---------------------------------------------------------------------------
__device__ __forceinline__ void bar_signal(unsigned* base, int g,
                                           unsigned subT, unsigned rootT,
                                           unsigned s)
{
    rel_drain();   // write-through stores already en route to coherence point
    unsigned old = __hip_atomic_fetch_add(base + g * 32, 1u, __ATOMIC_RELAXED,
                                          __HIP_MEMORY_SCOPE_AGENT);
    if (old == subT - 1u) {
        unsigned r = __hip_atomic_fetch_add(base + 256, 1u, __ATOMIC_RELAXED,
                                            __HIP_MEMORY_SCOPE_AGENT);
        if (r == rootT - 1u)
            __hip_atomic_store(base + 288, s, __ATOMIC_RELAXED,
                               __HIP_MEMORY_SCOPE_AGENT);
    }
}
__device__ __forceinline__ void bar_wait(unsigned* base, unsigned s)
{
    while (__hip_atomic_load(base + 288, __ATOMIC_RELAXED,
                             __HIP_MEMORY_SCOPE_AGENT) < s)
        __builtin_amdgcn_s_sleep(1);
    acq_inv();
}

// ---------------------------------------------------------------------------
// fp32 -> bf16 cast
// ---------------------------------------------------------------------------
__global__ __launch_bounds__(256) void cast_bf_k(
    const float* __restrict__ s, ushort_t* __restrict__ d, int n)
{
    int i = (blockIdx.x * 256 + threadIdx.x) * 4;
    if (i >= n) return;
    float4 v = *(const float4*)(s + i);
    ushort4 o;
    o.x = f2bf(v.x); o.y = f2bf(v.y); o.z = f2bf(v.z); o.w = f2bf(v.w);
    *(ushort4*)(d + i) = o;
}

// ---------------------------------------------------------------------------
// Phase-1 bf16 MFMA GEMM core (m97 structure), 128x128 tile, BK=32.
// ---------------------------------------------------------------------------
template<bool GATHER>
__device__ __forceinline__ void gemm_core(
    const ushort_t* __restrict__ A, int lda, int w0,
    const ushort_t* __restrict__ W, const float* __restrict__ bias,
    ushort_t* __restrict__ Cb, float* __restrict__ Cf, int ldc,
    int K, int m0, int n0, int co, int relu)
{
    __shared__ ushort_t As[128 * 32];
    __shared__ ushort_t Bs[128 * 32];
    const int tid = threadIdx.x;
    const int wave = tid >> 6, lane = tid & 63;
    const int wm = wave & 1, wn = wave >> 1;

    int r0 = m0 + (tid >> 2), r1 = r0 + 64;
    if (GATHER) {
        r0 = (w0 + (r0 >> 8)) * 16 + (r0 & 255);
        r1 = (w0 + (r1 >> 8)) * 16 + (r1 & 255);
    }
    const int kcol = (tid & 3) * 8;
    const ushort_t* gA0 = A + (size_t)r0 * lda + kcol;
    const ushort_t* gA1 = A + (size_t)r1 * lda + kcol;
    const ushort_t* pW  = W + (size_t)n0 * K;
    const ushort_t* gB0 = pW + (size_t)(tid >> 2) * K + kcol;
    const ushort_t* gB1 = gB0 + (size_t)64 * K;
    ushort_t* lA = As + wave * 512;
    ushort_t* lB = Bs + wave * 512;

    floatx4 acc[4][4];
#pragma unroll
    for (int i = 0; i < 4; ++i)
#pragma unroll
        for (int j = 0; j < 4; ++j) acc[i][j] = (floatx4){0.f, 0.f, 0.f, 0.f};

    const int fr = lane & 15, fk = (lane >> 4) * 8;
    const int arow = (wm * 64 + fr) * 32 + fk;
    const int brow = (wn * 64 + fr) * 32 + fk;

    for (int k0 = 0; k0 < K; k0 += 32) {
        GLDS(gA0 + k0, lA);
        GLDS(gA1 + k0, lA + 2048);
        GLDS(gB0 + k0, lB);
        GLDS(gB1 + k0, lB + 2048);
        __syncthreads();
        short8 a[4], b[4];
#pragma unroll
        for (int mi = 0; mi < 4; ++mi) a[mi] = *(const short8*)&As[arow + mi * 512];
#pragma unroll
        for (int ni = 0; ni < 4; ++ni) b[ni] = *(const short8*)&Bs[brow + ni * 512];
#pragma unroll
        for (int mi = 0; mi < 4; ++mi)
#pragma unroll
            for (int ni = 0; ni < 4; ++ni)
                acc[mi][ni] = __builtin_amdgcn_mfma_f32_16x16x32_bf16(
                    a[mi], b[ni], acc[mi][ni], 0, 0, 0);
        __syncthreads();
    }

    const int crq = (lane >> 4) * 4;
    const int ccol = lane & 15;
#pragma unroll
    for (int mi = 0; mi < 4; ++mi) {
#pragma unroll
        for (int ni = 0; ni < 4; ++ni) {
            int lc = wn * 64 + ni * 16 + ccol;
            float bz = bias[n0 + lc];
#pragma unroll
            for (int rg = 0; rg < 4; ++rg) {
                int row = m0 + wm * 64 + mi * 16 + crq + rg;
                float v = acc[mi][ni][rg] + bz;
                if (relu) v = fmaxf(v, 0.f);
                size_t off = (size_t)row * ldc + co + lc;
                if (Cb) Cb[off] = f2bf(v);
                if (Cf) Cf[off] = v;
            }
        }
    }
}

__global__ __launch_bounds__(256) void gemm_bf_k(
    const ushort_t* __restrict__ A, int lda,
    const ushort_t* __restrict__ W, const float* __restrict__ bias,
    ushort_t* __restrict__ Cb, float* __restrict__ Cf, int ldc,
    int K, int relu)
{
    gemm_core<false>(A, lda, 0, W, bias, Cb, Cf, ldc, K,
                     blockIdx.y * 128, blockIdx.x * 128, blockIdx.x * 128, relu);
}

__global__ __launch_bounds__(256) void gemm_qkv_k(
    const ushort_t* __restrict__ path_bf, const ushort_t* __restrict__ W,
    const float* __restrict__ bias, ushort_t* __restrict__ Cb, int w0)
{
    gemm_core<true>(path_bf, 1024, w0, W, bias, Cb, nullptr, 3072, 1024,
                    blockIdx.y * 128, blockIdx.x * 128, blockIdx.x * 128, 0);
}

// ---------------------------------------------------------------------------
// Shared MFMA attention core. Loads: normal cached. WT: O stores
// write-through (coop kernel); else normal (phase 1).
// ---------------------------------------------------------------------------
#define PLD 260
#define VLD 132

struct ScanShared {
    ushort_t P[64 * PLD];
    ushort_t VT[64 * VLD];
    float    l[64];
};

template<bool WT>
__device__ __forceinline__ void attn_core(
    int h, int rs, int tid,
    const ushort_t* __restrict__ Q, int ldq,
    const ushort_t* __restrict__ K, const ushort_t* __restrict__ V, int ldkv,
    ushort_t* __restrict__ O, int ldo, ScanShared& sh)
{
    const int wave = tid >> 6, lane = tid & 63;
    const int fr = lane & 15, q = lane >> 4, fk = q * 8;
    const ushort_t* Qh = Q + (size_t)(rs * 64) * ldq + h * 64;
    const ushort_t* Kh = K + h * 64;
    const ushort_t* Vh = V + h * 64;
    const int m0 = wave * 16;

    floatx4 s[16];
#pragma unroll
    for (int nt = 0; nt < 16; ++nt) s[nt] = (floatx4){0.f, 0.f, 0.f, 0.f};
#pragma unroll
    for (int kc = 0; kc < 64; kc += 32) {
        short8 a = *(const short8*)(Qh + (size_t)(m0 + fr) * ldq + kc + fk);
#pragma unroll
        for (int nt = 0; nt < 16; ++nt) {
            short8 b = *(const short8*)(Kh + (size_t)(nt * 16 + fr) * ldkv + kc + fk);
            s[nt] = __builtin_amdgcn_mfma_f32_16x16x32_bf16(a, b, s[nt], 0, 0, 0);
        }
    }

    float rmax[4] = {-INFINITY, -INFINITY, -INFINITY, -INFINITY};
#pragma unroll
    for (int nt = 0; nt < 16; ++nt)
#pragma unroll
        for (int rg = 0; rg < 4; ++rg) rmax[rg] = fmaxf(rmax[rg], s[nt][rg]);
#pragma unroll
    for (int d = 1; d < 16; d <<= 1)
#pragma unroll
        for (int rg = 0; rg < 4; ++rg)
            rmax[rg] = fmaxf(rmax[rg], __shfl_xor(rmax[rg], d));

    float rsum[4] = {0.f, 0.f, 0.f, 0.f};
#pragma unroll
    for (int nt = 0; nt < 16; ++nt) {
#pragma unroll
        for (int rg = 0; rg < 4; ++rg) {
            float p = __expf((s[nt][rg] - rmax[rg]) * 0.125f);
            rsum[rg] += p;
            sh.P[(m0 + q * 4 + rg) * PLD + nt * 16 + fr] = f2bf(p);
        }
    }
#pragma unroll
    for (int d = 1; d < 16; d <<= 1)
#pragma unroll
        for (int rg = 0; rg < 4; ++rg) rsum[rg] += __shfl_xor(rsum[rg], d);
    if (fr == 0) {
#pragma unroll
        for (int rg = 0; rg < 4; ++rg) sh.l[m0 + q * 4 + rg] = rsum[rg];
    }
    __syncthreads();

    floatx4 o[4];
#pragma unroll
    for (int i = 0; i < 4; ++i) o[i] = (floatx4){0.f, 0.f, 0.f, 0.f};

#pragma unroll
    for (int half = 0; half < 2; ++half) {
        {
            int r = tid & 127, cp = tid >> 7;
            const ushort_t* vrow = Vh + (size_t)(half * 128 + r) * ldkv + cp * 32;
#pragma unroll
            for (int c = 0; c < 4; ++c) {
                uint4 pk = *(const uint4*)(vrow + c * 8);
                int d0 = cp * 32 + c * 8;
                sh.VT[(d0 + 0) * VLD + r] = (ushort_t)(pk.x & 0xffff);
                sh.VT[(d0 + 1) * VLD + r] = (ushort_t)(pk.x >> 16);
                sh.VT[(d0 + 2) * VLD + r] = (ushort_t)(pk.y & 0xffff);
                sh.VT[(d0 + 3) * VLD + r] = (ushort_t)(pk.y >> 16);
                sh.VT[(d0 + 4) * VLD + r] = (ushort_t)(pk.z & 0xffff);
                sh.VT[(d0 + 5) * VLD + r] = (ushort_t)(pk.z >> 16);
                sh.VT[(d0 + 6) * VLD + r] = (ushort_t)(pk.w & 0xffff);
                sh.VT[(d0 + 7) * VLD + r] = (ushort_t)(pk.w >> 16);
            }
        }
        __syncthreads();
#pragma unroll
        for (int ks = 0; ks < 4; ++ks) {
            short8 a = *(const short8*)&sh.P[(m0 + fr) * PLD + half * 128 + ks * 32 + fk];
#pragma unroll
            for (int nt2 = 0; nt2 < 4; ++nt2) {
                short8 b = *(const short8*)&sh.VT[(nt2 * 16 + fr) * VLD + ks * 32 + fk];
                o[nt2] = __builtin_amdgcn_mfma_f32_16x16x32_bf16(a, b, o[nt2], 0, 0, 0);
            }
        }
        __syncthreads();
    }

    float linv[4];
#pragma unroll
    for (int rg = 0; rg < 4; ++rg) linv[rg] = 1.f / sh.l[m0 + q * 4 + rg];
#pragma unroll
    for (int nt2 = 0; nt2 < 4; ++nt2)
#pragma unroll
        for (int rg = 0; rg < 4; ++rg) {
            int row = rs * 64 + m0 + q * 4 + rg;
            ushort_t* op = O + (size_t)row * ldo + h * 64 + nt2 * 16 + fr;
            ushort_t v = f2bf(o[nt2][rg] * linv[rg]);
            if (WT) st2_wt(op, v); else *op = v;
        }
}

// Phase-1 standalone MFMA attention: grid (4 row-slices, NH, batch)
__global__ __launch_bounds__(256) void attn_mfma_k(
    const ushort_t* __restrict__ qkv, ushort_t* __restrict__ ao)
{
    __shared__ ScanShared sh;
    const int rs = blockIdx.x, h = blockIdx.y, b = blockIdx.z;
    const ushort_t* base = qkv + (size_t)b * TOK * 3072;
    attn_core<false>(h, rs, threadIdx.x, base, 3072, base + 1024, base + 2048,
                     3072, ao + (size_t)b * TOK * 1024, 1024, sh);
}

// ---------------------------------------------------------------------------
// Register-weight tall-skinny GEMM: C[256x16] = A[256x1024] @ Wreg^T + bz.
// A: normal cached loads. C: write-through bf16 stores (+ optional fp32).
// ---------------------------------------------------------------------------
__device__ __forceinline__ void ts_gemm_reg(
    const ushort_t* __restrict__ A, const short8* wreg, float bz,
    ushort_t* __restrict__ Cb, float* __restrict__ Cf, int ldc, int cc,
    int wave, int lane)
{
    const int fr = lane & 15, fk = (lane >> 4) * 8, q = lane >> 4;
    const int m0v = wave * 64;
    floatx4 acc[4];
#pragma unroll
    for (int i = 0; i < 4; ++i) acc[i] = (floatx4){0.f, 0.f, 0.f, 0.f};
    const ushort_t* aptr = A + (size_t)(m0v + fr) * 1024 + fk;
#pragma unroll
    for (int k = 0; k < 32; ++k) {
#pragma unroll
        for (int mi = 0; mi < 4; ++mi) {
            short8 a = *(const short8*)(aptr + (size_t)(mi * 16) * 1024 + k * 32);
            acc[mi] = __builtin_amdgcn_mfma_f32_16x16x32_bf16(a, wreg[k], acc[mi], 0, 0, 0);
        }
    }
#pragma unroll
    for (int mi = 0; mi < 4; ++mi) {
#pragma unroll
        for (int rg = 0; rg < 4; ++rg) {
            int row = m0v + mi * 16 + q * 4 + rg;
            float v = acc[mi][rg] + bz;
            size_t off = (size_t)row * ldc + cc + fr;
            st2_wt(Cb + off, f2bf(v));
            if (Cf) Cf[off] = v;
        }
    }
}

// ===========================================================================
// Cooperative phase-2 kernel. Grid 192 WGs x 256 thr (1 block/CU).
//  Role A (WGs 64..191): KV projection, weights in 128 VGPRs.
//  Role B+C (WGs 0..63): MFMA attention + out projection.
// Cross-WG stores write-through; barriers = vmcnt drain + atomic + inv.
// ===========================================================================
__global__ __launch_bounds__(256, 1) void scan_coop_k(
    const ushort_t* __restrict__ Qchunk, int i0, int w0, int nsteps,
    ushort_t* __restrict__ cum, ushort_t* __restrict__ KVb,
    ushort_t* __restrict__ AO2,
    const ushort_t* __restrict__ w_in2, const float* __restrict__ b_in2,
    const ushort_t* __restrict__ w_out2, const float* __restrict__ b_out2,
    float* __restrict__ outp, unsigned* __restrict__ bar, unsigned s0)
{
    __shared__ ScanShared sh;
    const int wg = blockIdx.x, tid = threadIdx.x;
    const int wave = tid >> 6, lane = tid & 63;
    const int fr = lane & 15, fk = (lane >> 4) * 8;
    unsigned* barA = bar;
    unsigned* barB = bar + 320;
    unsigned* barC = bar + 640;

    if (wg >= 64) {
        // ---------------- role A: KV = cum @ wkv^T ----------------
        const int n0 = (wg - 64) * 16;
        const int g = (wg - 64) & 7;
        short8 wreg[32];
        const ushort_t* Wn = w_in2 + (size_t)(1024 + n0 + fr) * 1024 + fk;
#pragma unroll
        for (int k = 0; k < 32; ++k) wreg[k] = *(const short8*)(Wn + k * 32);
        const float bz = b_in2[1024 + n0 + fr];

        unsigned s = s0;
        for (int t = 0; t < nsteps; ++t, ++s) {
            ts_gemm_reg(cum, wreg, bz, KVb, nullptr, 2048, n0, wave, lane);
            __syncthreads();
            if (tid == 0) {
                bar_signal(barA, g, 16u * s, 8u * s, s);   // publish KVb
                bar_wait(barC, s);                         // wait for cum_t
            }
            __syncthreads();
        }
    } else {
        // ---------------- role B+C ----------------
        const int h = wg >> 2, rs = wg & 3;     // stage B assignment
        const int n0 = wg * 16;                 // stage C columns
        const int g = wg & 3;
        short8 wreg[32];
        const ushort_t* Wn = w_out2 + (size_t)(n0 + fr) * 1024 + fk;
#pragma unroll
        for (int k = 0; k < 32; ++k) wreg[k] = *(const short8*)(Wn + k * 32);
        const float bz = b_out2[n0 + fr];

        unsigned s = s0;
        for (int t = 0; t < nsteps; ++t, ++s) {
            const int i = i0 + t;
            if (tid == 0) bar_wait(barA, s);    // KVb ready
            __syncthreads();
            attn_core<true>(h, rs, tid, Qchunk + (size_t)(i - w0) * WIN, 1024,
                            KVb, KVb + 1024, 2048, AO2, 1024, sh);
            __syncthreads();
            if (tid == 0) {
                bar_signal(barB, g, 16u * s, 4u * s, s);   // AO2 published
                bar_wait(barB, s);
            }
            __syncthreads();
            float* Cf = (i == N_WIN - 1) ? outp : nullptr;
            ts_gemm_reg(AO2, wreg, bz, cum, Cf, 1024, n0, wave, lane);
            __syncthreads();
            if (tid == 0) bar_signal(barC, g, 16u * s, 4u * s, s);  // cum ready
            __syncthreads();
        }
    }
}

// ---------------------------------------------------------------------------
extern "C" void kernel_launch(void* const* d_in, const int* in_sizes, int n_in,
                              void* d_out, int out_size, void* d_ws, size_t ws_size,
                              hipStream_t stream)
{
    const float* path   = (const float*)d_in[0];
    const float* w_in1  = (const float*)d_in[1];
    const float* b_in1  = (const float*)d_in[2];
    const float* w_out1 = (const float*)d_in[3];
    const float* b_out1 = (const float*)d_in[4];
    const float* w_lin  = (const float*)d_in[5];
    const float* b_lin  = (const float*)d_in[6];
    const float* w_in2  = (const float*)d_in[7];
    const float* b_in2  = (const float*)d_in[8];
    const float* w_out2 = (const float*)d_in[9];
    const float* b_out2 = (const float*)d_in[10];
    float* out = (float*)d_out;

    // workspace: barriers (8 KB) then bf16 buffers (~55 MB)
    unsigned* bar = (unsigned*)d_ws;
    ushort_t* ws = (ushort_t*)d_ws + 4096;
    ushort_t* path_bf  = ws;                              // 4096*1024
    ushort_t* w_in1_bf = path_bf  + (size_t)4096 * 1024;  // 3072*1024
    ushort_t* w_out1_bf= w_in1_bf + (size_t)3072 * 1024;
    ushort_t* w_lin_bf = w_out1_bf+ (size_t)1024 * 1024;
    ushort_t* w_in2_bf = w_lin_bf + (size_t)1024 * 1024;  // 3072*1024
    ushort_t* w_out2_bf= w_in2_bf + (size_t)3072 * 1024;
    ushort_t* qkv_bf   = w_out2_bf+ (size_t)1024 * 1024;  // 2048*3072
    ushort_t* ybuf_bf  = qkv_bf;                          // alias (qkv dead)
    ushort_t* ao_bf    = qkv_bf   + (size_t)2048 * 3072;  // 2048*1024
    ushort_t* Xchunk   = ao_bf    + (size_t)2048 * 1024;  // 2048*1024
    ushort_t* Qchunk   = Xchunk   + (size_t)2048 * 1024;  // 2048*1024
    ushort_t* KVb      = Qchunk   + (size_t)2048 * 1024;  // 256*2048
    ushort_t* AO2      = KVb + 2 * WIN;                   // 256*1024
    ushort_t* cum      = AO2 + WIN;                       // 256*1024

    hipMemsetAsync(bar, 0, 8192, stream);

    cast_bf_k<<<4096, 256, 0, stream>>>(path,  path_bf,  4096 * 1024);
    cast_bf_k<<<3072, 256, 0, stream>>>(w_in1, w_in1_bf, 3072 * 1024);
    cast_bf_k<<<1024, 256, 0, stream>>>(w_out1, w_out1_bf, 1024 * 1024);
    cast_bf_k<<<1024, 256, 0, stream>>>(w_lin, w_lin_bf, 1024 * 1024);
    cast_bf_k<<<3072, 256, 0, stream>>>(w_in2, w_in2_bf, 3072 * 1024);
    cast_bf_k<<<1024, 256, 0, stream>>>(w_out2, w_out2_bf, 1024 * 1024);

    unsigned sbase = 1;
    for (int c = 0; c < NCHUNK; ++c) {
        int w0 = c * CHUNK;
        // ---- Phase 1 for windows [w0, w0+CHUNK) ----
        gemm_qkv_k<<<dim3(24, 16), 256, 0, stream>>>(
            path_bf, w_in1_bf, b_in1, qkv_bf, w0);
        attn_mfma_k<<<dim3(4, NH, CHUNK), 256, 0, stream>>>(qkv_bf, ao_bf);
        gemm_bf_k<<<dim3(8, 16), 256, 0, stream>>>(
            ao_bf, 1024, w_out1_bf, b_out1, ybuf_bf, nullptr, 1024, 1024, 0);
        gemm_bf_k<<<dim3(8, 16), 256, 0, stream>>>(
            ybuf_bf, 1024, w_lin_bf, b_lin, Xchunk, nullptr, 1024, 1024, 1);
        // Q for the whole chunk (rows 0..1023 of w_in2 are wq)
        gemm_bf_k<<<dim3(8, 16), 256, 0, stream>>>(
            Xchunk, 1024, w_in2_bf, b_in2, Qchunk, nullptr, 1024, 1024, 0);

        // ---- Phase 2: one cooperative launch per chunk ----
        if (c == 0) {
            hipMemcpyAsync(cum, Xchunk, WIN * sizeof(ushort_t),
                           hipMemcpyDeviceToDevice, stream);
        }
        int i0 = (c == 0) ? 1 : w0;
        int nsteps = (c == 0) ? CHUNK - 1 : CHUNK;
        const ushort_t* QchunkP = Qchunk;
        ushort_t *cumP = cum, *KVbP = KVb, *AO2P = AO2;
        const ushort_t *win2P = w_in2_bf, *wout2P = w_out2_bf;
        const float *bin2P = b_in2, *bout2P = b_out2;
        float* outP = out;
        unsigned* barP = bar;
        unsigned sb = sbase;
        void* args[] = {&QchunkP, &i0, &w0, &nsteps, &cumP, &KVbP, &AO2P,
                        &win2P, &bin2P, &wout2P, &bout2P, &outP, &barP, &sb};
        hipLaunchCooperativeKernel((void*)scan_coop_k, dim3(192), dim3(256),
                                   args, 0, stream);
        sbase += (unsigned)nsteps;
    }
}

// Round 9
// 22310.587 us; speedup vs baseline: 1.7203x; 1.0506x over previous
//
#include <hip/hip_runtime.h>
#include <math.h>

// Problem constants
#define D_MODEL 1024
#define N_WIN   240
#define TOK     256
#define NH      16
#define DH      64
#define CHUNK   8
#define NCHUNK  30
#define WIN     ((size_t)TOK * D_MODEL)

typedef unsigned short ushort_t;
typedef unsigned long long ull_t;
typedef __attribute__((ext_vector_type(8))) short short8;
typedef __attribute__((ext_vector_type(4))) float floatx4;

__device__ __forceinline__ ushort_t f2bf(float f) {   // RNE
    unsigned u = __float_as_uint(f);
    unsigned lsb = (u >> 16) & 1u;
    u += 0x7fffu + lsb;
    return (ushort_t)(u >> 16);
}

// ---------------------------------------------------------------------------
// Coherence primitives.
//  - st2_wt: 2B write-through store (lands at coherence point / IC).
//  - ld8_sys / ld16_sys: system-scope relaxed loads (bypass L1/L2, read IC,
//    compiler-tracked vmcnt so they pipeline). Used ONLY for cum / AO2.
//  - No cache invalidation anywhere -> weights/Q stay L2-hot across steps.
// ---------------------------------------------------------------------------
__device__ __forceinline__ void st2_wt(ushort_t* p, ushort_t v) {
    unsigned vv = v;
    asm volatile("global_store_short %0, %1, off sc1"
                 :: "v"(p), "v"(vv) : "memory");
}
__device__ __forceinline__ void rel_drain() {
    asm volatile("s_waitcnt vmcnt(0)" ::: "memory");
}
__device__ __forceinline__ ull_t ld8_sys(const ushort_t* p) {
    return __hip_atomic_load((const ull_t*)p, __ATOMIC_RELAXED,
                             __HIP_MEMORY_SCOPE_SYSTEM);
}
__device__ __forceinline__ short8 ld16_sys(const ushort_t* p) {
    union { ull_t u[2]; short8 s; } c;
    c.u[0] = ld8_sys(p); c.u[1] = ld8_sys(p + 4);
    return c.s;
}

// async global->LDS, 16B per lane (phase-1 GEMM staging)
#define GLDS(g, l) __builtin_amdgcn_global_load_lds( \
    (const __attribute__((address_space(1))) unsigned int*)(g), \
    (__attribute__((address_space(3))) unsigned int*)(l), 16, 0, 0)

// ---------------------------------------------------------------------------
// Grid barrier (tree, fence-free): every thread drains its wave's stores
// (vmcnt 0), workgroup syncs, tid0 signals agent-scope counters and spins on
// the release word. 8 sub-counters x 8 arrivals, monotonic epoch s.
// ---------------------------------------------------------------------------
__device__ __forceinline__ void grid_bar(unsigned* base, int g, unsigned s)
{
    rel_drain();
    __syncthreads();
    if (threadIdx.x == 0) {
        unsigned old = __hip_atomic_fetch_add(base + g * 32, 1u,
                __ATOMIC_RELAXED, __HIP_MEMORY_SCOPE_AGENT);
        if (old == 8u * s - 1u) {
            unsigned r = __hip_atomic_fetch_add(base + 256, 1u,
                    __ATOMIC_RELAXED, __HIP_MEMORY_SCOPE_AGENT);
            if (r == 8u * s - 1u)
                __hip_atomic_store(base + 288, s, __ATOMIC_RELAXED,
                                   __HIP_MEMORY_SCOPE_AGENT);
        }
        while (__hip_atomic_load(base + 288, __ATOMIC_RELAXED,
                                 __HIP_MEMORY_SCOPE_AGENT) < s)
            __builtin_amdgcn_s_sleep(1);
    }
    __syncthreads();
}

// ---------------------------------------------------------------------------
// fp32 -> bf16 cast
// ---------------------------------------------------------------------------
__global__ __launch_bounds__(256) void cast_bf_k(
    const float* __restrict__ s, ushort_t* __restrict__ d, int n)
{
    int i = (blockIdx.x * 256 + threadIdx.x) * 4;
    if (i >= n) return;
    float4 v = *(const float4*)(s + i);
    ushort4 o;
    o.x = f2bf(v.x); o.y = f2bf(v.y); o.z = f2bf(v.z); o.w = f2bf(v.w);
    *(ushort4*)(d + i) = o;
}

// ---------------------------------------------------------------------------
// Phase-1 bf16 MFMA GEMM core (m97 structure), 128x128 tile, BK=32.
// ---------------------------------------------------------------------------
template<bool GATHER>
__device__ __forceinline__ void gemm_core(
    const ushort_t* __restrict__ A, int lda, int w0,
    const ushort_t* __restrict__ W, const float* __restrict__ bias,
    ushort_t* __restrict__ Cb, float* __restrict__ Cf, int ldc,
    int K, int m0, int n0, int co, int relu)
{
    __shared__ ushort_t As[128 * 32];
    __shared__ ushort_t Bs[128 * 32];
    const int tid = threadIdx.x;
    const int wave = tid >> 6, lane = tid & 63;
    const int wm = wave & 1, wn = wave >> 1;

    int r0 = m0 + (tid >> 2), r1 = r0 + 64;
    if (GATHER) {
        r0 = (w0 + (r0 >> 8)) * 16 + (r0 & 255);
        r1 = (w0 + (r1 >> 8)) * 16 + (r1 & 255);
    }
    const int kcol = (tid & 3) * 8;
    const ushort_t* gA0 = A + (size_t)r0 * lda + kcol;
    const ushort_t* gA1 = A + (size_t)r1 * lda + kcol;
    const ushort_t* pW  = W + (size_t)n0 * K;
    const ushort_t* gB0 = pW + (size_t)(tid >> 2) * K + kcol;
    const ushort_t* gB1 = gB0 + (size_t)64 * K;
    ushort_t* lA = As + wave * 512;
    ushort_t* lB = Bs + wave * 512;

    floatx4 acc[4][4];
#pragma unroll
    for (int i = 0; i < 4; ++i)
#pragma unroll
        for (int j = 0; j < 4; ++j) acc[i][j] = (floatx4){0.f, 0.f, 0.f, 0.f};

    const int fr = lane & 15, fk = (lane >> 4) * 8;
    const int arow = (wm * 64 + fr) * 32 + fk;
    const int brow = (wn * 64 + fr) * 32 + fk;

    for (int k0 = 0; k0 < K; k0 += 32) {
        GLDS(gA0 + k0, lA);
        GLDS(gA1 + k0, lA + 2048);
        GLDS(gB0 + k0, lB);
        GLDS(gB1 + k0, lB + 2048);
        __syncthreads();
        short8 a[4], b[4];
#pragma unroll
        for (int mi = 0; mi < 4; ++mi) a[mi] = *(const short8*)&As[arow + mi * 512];
#pragma unroll
        for (int ni = 0; ni < 4; ++ni) b[ni] = *(const short8*)&Bs[brow + ni * 512];
#pragma unroll
        for (int mi = 0; mi < 4; ++mi)
#pragma unroll
            for (int ni = 0; ni < 4; ++ni)
                acc[mi][ni] = __builtin_amdgcn_mfma_f32_16x16x32_bf16(
                    a[mi], b[ni], acc[mi][ni], 0, 0, 0);
        __syncthreads();
    }

    const int crq = (lane >> 4) * 4;
    const int ccol = lane & 15;
#pragma unroll
    for (int mi = 0; mi < 4; ++mi) {
#pragma unroll
        for (int ni = 0; ni < 4; ++ni) {
            int lc = wn * 64 + ni * 16 + ccol;
            float bz = bias[n0 + lc];
#pragma unroll
            for (int rg = 0; rg < 4; ++rg) {
                int row = m0 + wm * 64 + mi * 16 + crq + rg;
                float v = acc[mi][ni][rg] + bz;
                if (relu) v = fmaxf(v, 0.f);
                size_t off = (size_t)row * ldc + co + lc;
                if (Cb) Cb[off] = f2bf(v);
                if (Cf) Cf[off] = v;
            }
        }
    }
}

__global__ __launch_bounds__(256) void gemm_bf_k(
    const ushort_t* __restrict__ A, int lda,
    const ushort_t* __restrict__ W, const float* __restrict__ bias,
    ushort_t* __restrict__ Cb, float* __restrict__ Cf, int ldc,
    int K, int relu)
{
    gemm_core<false>(A, lda, 0, W, bias, Cb, Cf, ldc, K,
                     blockIdx.y * 128, blockIdx.x * 128, blockIdx.x * 128, relu);
}

__global__ __launch_bounds__(256) void gemm_qkv_k(
    const ushort_t* __restrict__ path_bf, const ushort_t* __restrict__ W,
    const float* __restrict__ bias, ushort_t* __restrict__ Cb, int w0)
{
    gemm_core<true>(path_bf, 1024, w0, W, bias, Cb, nullptr, 3072, 1024,
                    blockIdx.y * 128, blockIdx.x * 128, blockIdx.x * 128, 0);
}

// ---------------------------------------------------------------------------
// Phase-1 MFMA attention (unchanged, standalone kernel).
// ---------------------------------------------------------------------------
#define PLD 260
#define VLD 132

struct AttnShared {
    ushort_t P[64 * PLD];
    ushort_t VT[64 * VLD];
    float    l[64];
};

__device__ __forceinline__ void attn_core_p1(
    int h, int rs, int tid,
    const ushort_t* __restrict__ Q, int ldq,
    const ushort_t* __restrict__ K, const ushort_t* __restrict__ V, int ldkv,
    ushort_t* __restrict__ O, int ldo, AttnShared& sh)
{
    const int wave = tid >> 6, lane = tid & 63;
    const int fr = lane & 15, q = lane >> 4, fk = q * 8;
    const ushort_t* Qh = Q + (size_t)(rs * 64) * ldq + h * 64;
    const ushort_t* Kh = K + h * 64;
    const ushort_t* Vh = V + h * 64;
    const int m0 = wave * 16;

    floatx4 s[16];
#pragma unroll
    for (int nt = 0; nt < 16; ++nt) s[nt] = (floatx4){0.f, 0.f, 0.f, 0.f};
#pragma unroll
    for (int kc = 0; kc < 64; kc += 32) {
        short8 a = *(const short8*)(Qh + (size_t)(m0 + fr) * ldq + kc + fk);
#pragma unroll
        for (int nt = 0; nt < 16; ++nt) {
            short8 b = *(const short8*)(Kh + (size_t)(nt * 16 + fr) * ldkv + kc + fk);
            s[nt] = __builtin_amdgcn_mfma_f32_16x16x32_bf16(a, b, s[nt], 0, 0, 0);
        }
    }

    float rmax[4] = {-INFINITY, -INFINITY, -INFINITY, -INFINITY};
#pragma unroll
    for (int nt = 0; nt < 16; ++nt)
#pragma unroll
        for (int rg = 0; rg < 4; ++rg) rmax[rg] = fmaxf(rmax[rg], s[nt][rg]);
#pragma unroll
    for (int d = 1; d < 16; d <<= 1)
#pragma unroll
        for (int rg = 0; rg < 4; ++rg)
            rmax[rg] = fmaxf(rmax[rg], __shfl_xor(rmax[rg], d));

    float rsum[4] = {0.f, 0.f, 0.f, 0.f};
#pragma unroll
    for (int nt = 0; nt < 16; ++nt) {
#pragma unroll
        for (int rg = 0; rg < 4; ++rg) {
            float p = __expf((s[nt][rg] - rmax[rg]) * 0.125f);
            rsum[rg] += p;
            sh.P[(m0 + q * 4 + rg) * PLD + nt * 16 + fr] = f2bf(p);
        }
    }
#pragma unroll
    for (int d = 1; d < 16; d <<= 1)
#pragma unroll
        for (int rg = 0; rg < 4; ++rg) rsum[rg] += __shfl_xor(rsum[rg], d);
    if (fr == 0) {
#pragma unroll
        for (int rg = 0; rg < 4; ++rg) sh.l[m0 + q * 4 + rg] = rsum[rg];
    }
    __syncthreads();

    floatx4 o[4];
#pragma unroll
    for (int i = 0; i < 4; ++i) o[i] = (floatx4){0.f, 0.f, 0.f, 0.f};

#pragma unroll
    for (int half = 0; half < 2; ++half) {
        {
            int r = tid & 127, cp = tid >> 7;
            const ushort_t* vrow = Vh + (size_t)(half * 128 + r) * ldkv + cp * 32;
#pragma unroll
            for (int c = 0; c < 4; ++c) {
                uint4 pk = *(const uint4*)(vrow + c * 8);
                int d0 = cp * 32 + c * 8;
                sh.VT[(d0 + 0) * VLD + r] = (ushort_t)(pk.x & 0xffff);
                sh.VT[(d0 + 1) * VLD + r] = (ushort_t)(pk.x >> 16);
                sh.VT[(d0 + 2) * VLD + r] = (ushort_t)(pk.y & 0xffff);
                sh.VT[(d0 + 3) * VLD + r] = (ushort_t)(pk.y >> 16);
                sh.VT[(d0 + 4) * VLD + r] = (ushort_t)(pk.z & 0xffff);
                sh.VT[(d0 + 5) * VLD + r] = (ushort_t)(pk.z >> 16);
                sh.VT[(d0 + 6) * VLD + r] = (ushort_t)(pk.w & 0xffff);
                sh.VT[(d0 + 7) * VLD + r] = (ushort_t)(pk.w >> 16);
            }
        }
        __syncthreads();
#pragma unroll
        for (int ks = 0; ks < 4; ++ks) {
            short8 a = *(const short8*)&sh.P[(m0 + fr) * PLD + half * 128 + ks * 32 + fk];
#pragma unroll
            for (int nt2 = 0; nt2 < 4; ++nt2) {
                short8 b = *(const short8*)&sh.VT[(nt2 * 16 + fr) * VLD + ks * 32 + fk];
                o[nt2] = __builtin_amdgcn_mfma_f32_16x16x32_bf16(a, b, o[nt2], 0, 0, 0);
            }
        }
        __syncthreads();
    }

    float linv[4];
#pragma unroll
    for (int rg = 0; rg < 4; ++rg) linv[rg] = 1.f / sh.l[m0 + q * 4 + rg];
#pragma unroll
    for (int nt2 = 0; nt2 < 4; ++nt2)
#pragma unroll
        for (int rg = 0; rg < 4; ++rg) {
            int row = rs * 64 + m0 + q * 4 + rg;
            O[(size_t)row * ldo + h * 64 + nt2 * 16 + fr] =
                f2bf(o[nt2][rg] * linv[rg]);
        }
}

__global__ __launch_bounds__(256) void attn_mfma_k(
    const ushort_t* __restrict__ qkv, ushort_t* __restrict__ ao)
{
    __shared__ AttnShared sh;
    const int rs = blockIdx.x, h = blockIdx.y, b = blockIdx.z;
    const ushort_t* base = qkv + (size_t)b * TOK * 3072;
    attn_core_p1(h, rs, threadIdx.x, base, 3072, base + 1024, base + 2048,
                 3072, ao + (size_t)b * TOK * 1024, 1024, sh);
}

// ===========================================================================
// Cooperative phase-2 kernel, redesigned.
// Grid 64 WGs x 256 thr. WG = (head h = wg>>2, row-slice rs = wg&3).
// Per step:
//   [barC from prev step guarantees cum fresh]
//   1. KV build: K_h,V_h = cum @ {wk,wv}_h^T + b  -> LDS (V transposed).
//      cum via ld8_sys (IC-coherent), weights via cached loads (L2-hot).
//   2. attention for rows [rs*64, rs*64+64): S=QK^T, softmax, P->LDS, PV.
//      O slice -> AO2 via write-through stores.
//   3. barB -> out-proj: cum[rs rows, 16 cols of head h] from AO2 (ld8_sys)
//      @ wout cols (cached). -> cum via WT (+ fp32 out on last step).
//   4. barC.
// ===========================================================================
#define KLD 72    // Kl stride (144 B = 16*9, b128-aligned)
#define TLD 264   // Vt / P stride (528 B = 16*33)

struct ScanShared {
    ushort_t Kl[256 * KLD];   // K_h [key][dim]     36864 B
    ushort_t Vt[64 * TLD];    // V_h^T [dim][key]   33792 B
    ushort_t P [64 * TLD];    // probs [row][key]   33792 B
};

__global__ __launch_bounds__(256, 1) void scan_coop_k(
    const ushort_t* __restrict__ Qchunk, int i0, int w0, int nsteps,
    ushort_t* __restrict__ cum, ushort_t* __restrict__ AO2,
    const ushort_t* __restrict__ w_in2, const float* __restrict__ b_in2,
    const ushort_t* __restrict__ w_out2, const float* __restrict__ b_out2,
    float* __restrict__ outp, unsigned* __restrict__ bar, unsigned s0)
{
    __shared__ ScanShared sh;
    const int wg = blockIdx.x, tid = threadIdx.x;
    const int h = wg >> 2, rs = wg & 3;
    const int wave = tid >> 6, lane = tid & 63;
    const int fr = lane & 15, q = lane >> 4, fk = q * 8;
    const int g = wg & 7;
    unsigned* barB = bar;
    unsigned* barC = bar + 512;

    // weight row pointers (cached loads; stay L2-hot — no invalidation ever)
    const ushort_t* wkv[8];
#pragma unroll
    for (int nt = 0; nt < 4; ++nt) {
        wkv[nt]     = w_in2 + (size_t)(1024 + h * 64 + nt * 16 + fr) * 1024 + fk;
        wkv[nt + 4] = w_in2 + (size_t)(2048 + h * 64 + nt * 16 + fr) * 1024 + fk;
    }
    const ushort_t* wo = w_out2 + (size_t)(h * 16 + fr) * 1024 + fk;
    float bk[4], bv[4];
#pragma unroll
    for (int nt = 0; nt < 4; ++nt) {
        bk[nt] = b_in2[1024 + h * 64 + nt * 16 + fr];
        bv[nt] = b_in2[2048 + h * 64 + nt * 16 + fr];
    }
    const float bzo = b_out2[h * 16 + fr];

    unsigned s = s0;
    for (int t = 0; t < nsteps; ++t, ++s) {
        const int i = i0 + t;

        // ---------- 1. KV build into LDS ----------
        {
            floatx4 acc[4][8];
#pragma unroll
            for (int mt = 0; mt < 4; ++mt)
#pragma unroll
                for (int nt = 0; nt < 8; ++nt)
                    acc[mt][nt] = (floatx4){0.f, 0.f, 0.f, 0.f};
            const ushort_t* arow0 = cum + (size_t)(wave * 64 + fr) * 1024 + fk;
            for (int k0 = 0; k0 < 1024; k0 += 32) {
                short8 a[4];
#pragma unroll
                for (int mt = 0; mt < 4; ++mt)
                    a[mt] = ld16_sys(arow0 + (size_t)(mt * 16) * 1024 + k0);
#pragma unroll
                for (int nt = 0; nt < 8; ++nt) {
                    short8 b = *(const short8*)(wkv[nt] + k0);
#pragma unroll
                    for (int mt = 0; mt < 4; ++mt)
                        acc[mt][nt] = __builtin_amdgcn_mfma_f32_16x16x32_bf16(
                            a[mt], b, acc[mt][nt], 0, 0, 0);
                }
            }
            // epilogue: K -> Kl[key][dim], V -> Vt[dim][key]
#pragma unroll
            for (int mt = 0; mt < 4; ++mt) {
#pragma unroll
                for (int nt = 0; nt < 4; ++nt) {
#pragma unroll
                    for (int rg = 0; rg < 4; ++rg) {
                        int key = wave * 64 + mt * 16 + q * 4 + rg;
                        sh.Kl[key * KLD + nt * 16 + fr] =
                            f2bf(acc[mt][nt][rg] + bk[nt]);
                    }
                    ushort4 pv;
                    pv.x = f2bf(acc[mt][nt + 4][0] + bv[nt]);
                    pv.y = f2bf(acc[mt][nt + 4][1] + bv[nt]);
                    pv.z = f2bf(acc[mt][nt + 4][2] + bv[nt]);
                    pv.w = f2bf(acc[mt][nt + 4][3] + bv[nt]);
                    int key0 = wave * 64 + mt * 16 + q * 4;
                    *(ushort4*)&sh.Vt[(nt * 16 + fr) * TLD + key0] = pv;
                }
            }
        }
        __syncthreads();

        // ---------- 2. attention (rows rs*64 + wave*16 .. +16) ----------
        float rsum[4];
        {
            const ushort_t* Qrow = Qchunk + (size_t)(i - w0) * WIN
                + (size_t)(rs * 64 + wave * 16 + fr) * 1024 + h * 64;
            floatx4 sc[16];
#pragma unroll
            for (int nt = 0; nt < 16; ++nt) sc[nt] = (floatx4){0.f, 0.f, 0.f, 0.f};
#pragma unroll
            for (int kc = 0; kc < 64; kc += 32) {
                short8 a = *(const short8*)(Qrow + kc);
#pragma unroll
                for (int nt = 0; nt < 16; ++nt) {
                    short8 b = *(const short8*)&sh.Kl[(nt * 16 + fr) * KLD + kc + fk];
                    sc[nt] = __builtin_amdgcn_mfma_f32_16x16x32_bf16(a, b, sc[nt], 0, 0, 0);
                }
            }
            float rmax[4] = {-INFINITY, -INFINITY, -INFINITY, -INFINITY};
#pragma unroll
            for (int nt = 0; nt < 16; ++nt)
#pragma unroll
                for (int rg = 0; rg < 4; ++rg) rmax[rg] = fmaxf(rmax[rg], sc[nt][rg]);
#pragma unroll
            for (int d = 1; d < 16; d <<= 1)
#pragma unroll
                for (int rg = 0; rg < 4; ++rg)
                    rmax[rg] = fmaxf(rmax[rg], __shfl_xor(rmax[rg], d));
#pragma unroll
            for (int rg = 0; rg < 4; ++rg) rsum[rg] = 0.f;
#pragma unroll
            for (int nt = 0; nt < 16; ++nt) {
#pragma unroll
                for (int rg = 0; rg < 4; ++rg) {
                    float p = __expf((sc[nt][rg] - rmax[rg]) * 0.125f);
                    rsum[rg] += p;
                    sh.P[(wave * 16 + q * 4 + rg) * TLD + nt * 16 + fr] = f2bf(p);
                }
            }
#pragma unroll
            for (int d = 1; d < 16; d <<= 1)
#pragma unroll
                for (int rg = 0; rg < 4; ++rg) rsum[rg] += __shfl_xor(rsum[rg], d);
        }
        // PV (P rows are per-wave; Vt cross-wave already synced)
        {
            floatx4 o[4];
#pragma unroll
            for (int nt = 0; nt < 4; ++nt) o[nt] = (floatx4){0.f, 0.f, 0.f, 0.f};
#pragma unroll
            for (int kt = 0; kt < 8; ++kt) {
                short8 a = *(const short8*)&sh.P[(wave * 16 + fr) * TLD + kt * 32 + fk];
#pragma unroll
                for (int nt = 0; nt < 4; ++nt) {
                    short8 b = *(const short8*)&sh.Vt[(nt * 16 + fr) * TLD + kt * 32 + fk];
                    o[nt] = __builtin_amdgcn_mfma_f32_16x16x32_bf16(a, b, o[nt], 0, 0, 0);
                }
            }
            float linv[4];
#pragma unroll
            for (int rg = 0; rg < 4; ++rg) linv[rg] = 1.f / rsum[rg];
#pragma unroll
            for (int nt = 0; nt < 4; ++nt)
#pragma unroll
                for (int rg = 0; rg < 4; ++rg) {
                    int row = rs * 64 + wave * 16 + q * 4 + rg;
                    st2_wt(AO2 + (size_t)row * 1024 + h * 64 + nt * 16 + fr,
                           f2bf(o[nt][rg] * linv[rg]));
                }
        }
        grid_bar(barB, g, s);   // AO2 complete

        // ---------- 3. out-projection ----------
        {
            floatx4 c = (floatx4){0.f, 0.f, 0.f, 0.f};
            const ushort_t* arow = AO2 + (size_t)(rs * 64 + wave * 16 + fr) * 1024 + fk;
            for (int k0 = 0; k0 < 1024; k0 += 32) {
                short8 a = ld16_sys(arow + k0);
                short8 b = *(const short8*)(wo + k0);
                c = __builtin_amdgcn_mfma_f32_16x16x32_bf16(a, b, c, 0, 0, 0);
            }
#pragma unroll
            for (int rg = 0; rg < 4; ++rg) {
                int row = rs * 64 + wave * 16 + q * 4 + rg;
                float v = c[rg] + bzo;
                size_t off = (size_t)row * 1024 + h * 16 + fr;
                st2_wt(cum + off, f2bf(v));
                if (i == N_WIN - 1) outp[off] = v;
            }
        }
        grid_bar(barC, g, s);   // cum complete
    }
}

// ---------------------------------------------------------------------------
extern "C" void kernel_launch(void* const* d_in, const int* in_sizes, int n_in,
                              void* d_out, int out_size, void* d_ws, size_t ws_size,
                              hipStream_t stream)
{
    const float* path   = (const float*)d_in[0];
    const float* w_in1  = (const float*)d_in[1];
    const float* b_in1  = (const float*)d_in[2];
    const float* w_out1 = (const float*)d_in[3];
    const float* b_out1 = (const float*)d_in[4];
    const float* w_lin  = (const float*)d_in[5];
    const float* b_lin  = (const float*)d_in[6];
    const float* w_in2  = (const float*)d_in[7];
    const float* b_in2  = (const float*)d_in[8];
    const float* w_out2 = (const float*)d_in[9];
    const float* b_out2 = (const float*)d_in[10];
    float* out = (float*)d_out;

    // workspace: barriers (8 KB) then bf16 buffers (~55 MB)
    unsigned* bar = (unsigned*)d_ws;
    ushort_t* ws = (ushort_t*)d_ws + 4096;
    ushort_t* path_bf  = ws;                              // 4096*1024
    ushort_t* w_in1_bf = path_bf  + (size_t)4096 * 1024;  // 3072*1024
    ushort_t* w_out1_bf= w_in1_bf + (size_t)3072 * 1024;
    ushort_t* w_lin_bf = w_out1_bf+ (size_t)1024 * 1024;
    ushort_t* w_in2_bf = w_lin_bf + (size_t)1024 * 1024;  // 3072*1024
    ushort_t* w_out2_bf= w_in2_bf + (size_t)3072 * 1024;
    ushort_t* qkv_bf   = w_out2_bf+ (size_t)1024 * 1024;  // 2048*3072
    ushort_t* ybuf_bf  = qkv_bf;                          // alias (qkv dead)
    ushort_t* ao_bf    = qkv_bf   + (size_t)2048 * 3072;  // 2048*1024
    ushort_t* Xchunk   = ao_bf    + (size_t)2048 * 1024;  // 2048*1024
    ushort_t* Qchunk   = Xchunk   + (size_t)2048 * 1024;  // 2048*1024
    ushort_t* AO2      = Qchunk   + (size_t)2048 * 1024;  // 256*1024
    ushort_t* cum      = AO2 + WIN;                       // 256*1024

    hipMemsetAsync(bar, 0, 8192, stream);

    cast_bf_k<<<4096, 256, 0, stream>>>(path,  path_bf,  4096 * 1024);
    cast_bf_k<<<3072, 256, 0, stream>>>(w_in1, w_in1_bf, 3072 * 1024);
    cast_bf_k<<<1024, 256, 0, stream>>>(w_out1, w_out1_bf, 1024 * 1024);
    cast_bf_k<<<1024, 256, 0, stream>>>(w_lin, w_lin_bf, 1024 * 1024);
    cast_bf_k<<<3072, 256, 0, stream>>>(w_in2, w_in2_bf, 3072 * 1024);
    cast_bf_k<<<1024, 256, 0, stream>>>(w_out2, w_out2_bf, 1024 * 1024);

    unsigned sbase = 1;
    for (int c = 0; c < NCHUNK; ++c) {
        int w0 = c * CHUNK;
        // ---- Phase 1 for windows [w0, w0+CHUNK) ----
        gemm_qkv_k<<<dim3(24, 16), 256, 0, stream>>>(
            path_bf, w_in1_bf, b_in1, qkv_bf, w0);
        attn_mfma_k<<<dim3(4, NH, CHUNK), 256, 0, stream>>>(qkv_bf, ao_bf);
        gemm_bf_k<<<dim3(8, 16), 256, 0, stream>>>(
            ao_bf, 1024, w_out1_bf, b_out1, ybuf_bf, nullptr, 1024, 1024, 0);
        gemm_bf_k<<<dim3(8, 16), 256, 0, stream>>>(
            ybuf_bf, 1024, w_lin_bf, b_lin, Xchunk, nullptr, 1024, 1024, 1);
        // Q for the whole chunk (rows 0..1023 of w_in2 are wq)
        gemm_bf_k<<<dim3(8, 16), 256, 0, stream>>>(
            Xchunk, 1024, w_in2_bf, b_in2, Qchunk, nullptr, 1024, 1024, 0);

        // ---- Phase 2: one cooperative launch per chunk ----
        if (c == 0) {
            hipMemcpyAsync(cum, Xchunk, WIN * sizeof(ushort_t),
                           hipMemcpyDeviceToDevice, stream);
        }
        int i0 = (c == 0) ? 1 : w0;
        int nsteps = (c == 0) ? CHUNK - 1 : CHUNK;
        const ushort_t* QchunkP = Qchunk;
        ushort_t *cumP = cum, *AO2P = AO2;
        const ushort_t *win2P = w_in2_bf, *wout2P = w_out2_bf;
        const float *bin2P = b_in2, *bout2P = b_out2;
        float* outP = out;
        unsigned* barP = bar;
        unsigned sb = sbase;
        void* args[] = {&QchunkP, &i0, &w0, &nsteps, &cumP, &AO2P,
                        &win2P, &bin2P, &wout2P, &bout2P, &outP, &barP, &sb};
        hipLaunchCooperativeKernel((void*)scan_coop_k, dim3(64), dim3(256),
                                   args, 0, stream);
        sbase += (unsigned)nsteps;
    }
}